// Round 10
// baseline (264.345 us; speedup 1.0000x reference)
//
#include <hip/hip_runtime.h>

// GraphFilter on MI355X: out = (1/3 + (2/3)/rs_i) X + (2/3) dinv_i * (A @ (dinv .* X))
// A = thr(F F^T, 1e-10), diag 0; rs = rowsum(A)+1; dinv = rs^-1/2.
// R10: revert R9's nt stores + swizzle (WRITE amplification 93->212 MB).
// Base = R7 (182 us). Single change: simgemm K-loop is barrier-free with
// REGISTER double-buffered fragment prefetch (AITER-style): issue next
// 64-K group's global loads before the current group's 16 MFMAs, so
// compiler-placed s_waitcnt gets ~150+ cyc of cover. LDS only for epilogue.

#define NR 8192
#define DC 512
#define KZN 4

typedef unsigned short u16;
typedef signed char i8;
typedef float f32x4 __attribute__((ext_vector_type(4)));
typedef int i32x4 __attribute__((ext_vector_type(4)));
typedef u16 u16x4 __attribute__((ext_vector_type(4)));

// quant scales
#define QF_INV 453.5714285f      // 127/0.28  (|F| <= ~0.25)
#define DEQA   4.8608093e-6f     // (0.28/127)^2
#define QS_INV 254.0f            // 127/0.5   (S in [0,0.5))
#define QY_INV 211.6666666f      // 127/0.6   (|Yt| <= ~0.53)
#define DEQ    1.8600229e-5f     // (0.5/127)*(0.6/127)

__device__ __forceinline__ float bf2f(u16 u) {
  union { unsigned u; float f; } v; v.u = ((unsigned)u) << 16; return v.f;
}
__device__ __forceinline__ u16 f2bf(float f) {
  union { float f; unsigned u; } v; v.f = f;
  unsigned r = v.u + 0x7fffu + ((v.u >> 16) & 1u);
  return (u16)(r >> 16);
}

// async 16B global->LDS (wave-uniform LDS base + lane*16 semantics)
__device__ __forceinline__ void async16(const void* ga, void* la) {
  __builtin_amdgcn_global_load_lds(
      (const __attribute__((address_space(1))) unsigned int*)ga,
      (__attribute__((address_space(3))) unsigned int*)la, 16, 0, 0);
}

// ---- i8 staging, 128-byte rows (BK=128): ROWSx128 i8 tile, NT threads ----
// Phys 16B slot s (row r = s>>3, phys chunk c = s&7) holds global chunk
// kq = c ^ (r&7): XOR spreads fragment ds_read_b128s across bank groups.
template <int ROWS, int NT>
__device__ __forceinline__ void stage_i8_k128(const i8* __restrict__ g, int ld,
                                              int row0, int k0, i8* lds, int tid) {
  constexpr int PER = (ROWS * 8) / NT;
#pragma unroll
  for (int q = 0; q < PER; ++q) {
    int s = q * NT + tid;
    int r = s >> 3;
    int kq = (s & 7) ^ (r & 7);
    async16(g + (size_t)(row0 + r) * ld + (k0 + kq * 16), lds + s * 16);
  }
}
// fragment: row m, chunk c = kc*4 + quad (c in 0..7)
__device__ __forceinline__ i32x4 frag_i8_k128(const i8* lds, int m, int c) {
  int phys = c ^ (m & 7);
  return *(const i32x4*)(lds + m * 128 + phys * 16);
}

// ---------- kernel 1: row L2-normalize X -> F (i8); zero rs_partial ----------
__global__ __launch_bounds__(256) void k_normalize(const float* __restrict__ X,
                                                   i8* __restrict__ F,
                                                   float* __restrict__ rs_partial) {
  int row = blockIdx.x;
  int tid = threadIdx.x;
  if (tid == 0) rs_partial[row] = 0.f;
  const float* xr = X + (size_t)row * DC;
  float2 v = *(const float2*)(xr + 2 * tid);
  float s = v.x * v.x + v.y * v.y;
#pragma unroll
  for (int off = 32; off; off >>= 1) s += __shfl_down(s, off);
  __shared__ float wsum[4];
  if ((tid & 63) == 0) wsum[tid >> 6] = s;
  __syncthreads();
  float tot = wsum[0] + wsum[1] + wsum[2] + wsum[3];
  float scale = QF_INV / fmaxf(sqrtf(tot), 1e-12f);
  int q0 = (int)rintf(v.x * scale);
  int q1 = (int)rintf(v.y * scale);
  q0 = q0 > 127 ? 127 : (q0 < -127 ? -127 : q0);
  q1 = q1 > 127 ? 127 : (q1 < -127 ? -127 : q1);
  u16 pk = (u16)((q0 & 255) | ((q1 & 255) << 8));
  ((u16*)(F + (size_t)row * DC))[tid] = pk;
}

// ---------- kernel 2: symmetric S = thr(F F^T), diag 0, i8 in / i8 out ----------
// Barrier-free K-loop with register double-buffered fragment prefetch.
// ti<=tj tiles only; mirror via 32 KB LDS transpose in the epilogue.
__global__ __launch_bounds__(256, 3) void k_simgemm(const i8* __restrict__ F,
                                                    i8* __restrict__ S,
                                                    float* __restrict__ rs_partial) {
  __shared__ alignas(16) char smem[32768];  // epilogue transpose only
  int tid = threadIdx.x, lane = tid & 63, wave = tid >> 6;
  // triangle decode: block -> (ti <= tj)
  int b = blockIdx.x;
  int tj = (int)((sqrtf(8.f * b + 1.f) - 1.f) * 0.5f);
  while ((tj + 1) * (tj + 2) / 2 <= b) ++tj;
  while (tj * (tj + 1) / 2 > b) --tj;
  int ti = b - tj * (tj + 1) / 2;
  bool diag = (ti == tj);

  int wm = wave >> 1, wn = wave & 1;
  int quad = lane >> 4, col = lane & 15;
  i32x4 zero = {0, 0, 0, 0};
  i32x4 acc[4][4];
#pragma unroll
  for (int a = 0; a < 4; ++a)
#pragma unroll
    for (int c = 0; c < 4; ++c) acc[a][c] = zero;

  // per-lane fragment pointers: lane covers row (base+col), 16 B at k-offset
  const i8* pa = F + ((ti * 128 + wm * 64 + col) * DC + quad * 16);
  const i8* pb = F + ((tj * 128 + wn * 64 + col) * DC + quad * 16);
  bool reuse = diag && (wm == wn);

  i32x4 a0[4], b0[4], a1[4], b1[4];
#pragma unroll
  for (int mi = 0; mi < 4; ++mi) a0[mi] = *(const i32x4*)(pa + mi * 16 * DC + 0);
  if (!reuse) {
#pragma unroll
    for (int ni = 0; ni < 4; ++ni) b0[ni] = *(const i32x4*)(pb + ni * 16 * DC + 0);
  }
#pragma unroll
  for (int mi = 0; mi < 4; ++mi) a1[mi] = *(const i32x4*)(pa + mi * 16 * DC + 64);
  if (!reuse) {
#pragma unroll
    for (int ni = 0; ni < 4; ++ni) b1[ni] = *(const i32x4*)(pb + ni * 16 * DC + 64);
  }

#pragma unroll
  for (int kt = 0; kt < DC; kt += 128) {
    // compute group kt on (a0,b0); refill (a0,b0) with kt+128
    {
      i32x4* B = reuse ? a0 : b0;
#pragma unroll
      for (int mi = 0; mi < 4; ++mi)
#pragma unroll
        for (int ni = 0; ni < 4; ++ni)
          acc[mi][ni] = __builtin_amdgcn_mfma_i32_16x16x64_i8(a0[mi], B[ni], acc[mi][ni], 0, 0, 0);
      if (kt + 128 < DC) {
#pragma unroll
        for (int mi = 0; mi < 4; ++mi) a0[mi] = *(const i32x4*)(pa + mi * 16 * DC + kt + 128);
        if (!reuse) {
#pragma unroll
          for (int ni = 0; ni < 4; ++ni) b0[ni] = *(const i32x4*)(pb + ni * 16 * DC + kt + 128);
        }
      }
    }
    // compute group kt+64 on (a1,b1); refill with kt+192
    {
      i32x4* B = reuse ? a1 : b1;
#pragma unroll
      for (int mi = 0; mi < 4; ++mi)
#pragma unroll
        for (int ni = 0; ni < 4; ++ni)
          acc[mi][ni] = __builtin_amdgcn_mfma_i32_16x16x64_i8(a1[mi], B[ni], acc[mi][ni], 0, 0, 0);
      if (kt + 192 < DC) {
#pragma unroll
        for (int mi = 0; mi < 4; ++mi) a1[mi] = *(const i32x4*)(pa + mi * 16 * DC + kt + 192);
        if (!reuse) {
#pragma unroll
          for (int ni = 0; ni < 4; ++ni) b1[ni] = *(const i32x4*)(pb + ni * 16 * DC + kt + 192);
        }
      }
    }
  }

  // dequant + threshold + diag-zero; fused exact column sums and row sums
  float av[4][4][4];
  float cs[4] = {0.f, 0.f, 0.f, 0.f};
  float rv[16];
#pragma unroll
  for (int u = 0; u < 16; ++u) rv[u] = 0.f;
#pragma unroll
  for (int mi = 0; mi < 4; ++mi) {
#pragma unroll
    for (int r = 0; r < 4; ++r) {
      int gi = ti * 128 + wm * 64 + mi * 16 + quad * 4 + r;
#pragma unroll
      for (int ni = 0; ni < 4; ++ni) {
        int gj = tj * 128 + wn * 64 + ni * 16 + col;
        float v = (float)acc[mi][ni][r] * DEQA;
        if (v < 1e-10f || gi == gj) v = 0.f;
        av[mi][ni][r] = v;
        cs[ni] += v;
        rv[mi * 4 + r] += v;
      }
    }
  }
#pragma unroll
  for (int ni = 0; ni < 4; ++ni) {
    float c = cs[ni];
    c += __shfl_xor(c, 16);
    c += __shfl_xor(c, 32);
    if (quad == 0) {
      int gj = tj * 128 + wn * 64 + ni * 16 + col;
      atomicAdd(&rs_partial[gj], c);
    }
  }
  if (!diag) {
#pragma unroll
    for (int u = 0; u < 16; ++u) {
      float c = rv[u];
      c += __shfl_xor(c, 1);
      c += __shfl_xor(c, 2);
      c += __shfl_xor(c, 4);
      c += __shfl_xor(c, 8);
      if (col == 0) {
        int mi = u >> 2, r = u & 3;
        int gi = ti * 128 + wm * 64 + mi * 16 + quad * 4 + r;
        atomicAdd(&rs_partial[gi], c);
      }
    }
  }

  // quantize + single-pass LDS transpose; 16B-chunk XOR swizzle per row
  char* direct = smem;           // 128x128 i8 = 16 KB
  char* mirror = smem + 16384;   // 128x128 i8 = 16 KB
#pragma unroll
  for (int mi = 0; mi < 4; ++mi) {
#pragma unroll
    for (int ni = 0; ni < 4; ++ni) {
      int cg = wn * 64 + ni * 16 + col;
      int q[4];
#pragma unroll
      for (int r = 0; r < 4; ++r) {
        int qq = (int)rintf(av[mi][ni][r] * QS_INV);
        q[r] = qq > 127 ? 127 : qq;
      }
#pragma unroll
      for (int r = 0; r < 4; ++r) {
        int row = wm * 64 + mi * 16 + quad * 4 + r;
        int chunk = (cg >> 4) ^ (row & 7);
        direct[row * 128 + chunk * 16 + (cg & 15)] = (char)q[r];
      }
      if (!diag) {
        int mcb = wm * 64 + mi * 16 + quad * 4;
        int chunk = (mcb >> 4) ^ (cg & 7);
        unsigned pk = (unsigned)(q[0] & 255) | ((unsigned)(q[1] & 255) << 8) |
                      ((unsigned)(q[2] & 255) << 16) | ((unsigned)(q[3] & 255) << 24);
        *(unsigned*)(mirror + cg * 128 + chunk * 16 + (mcb & 15)) = pk;
      }
    }
  }
  __syncthreads();
  // coalesced 16B global stores (normal, L2-cached: R9 showed nt amplifies)
  {
    int r2 = tid >> 1, half = tid & 1;
#pragma unroll
    for (int k = 0; k < 4; ++k) {
      int c = half * 4 + k;
      int phys = c ^ (r2 & 7);
      i32x4 d = *(const i32x4*)(direct + r2 * 128 + phys * 16);
      *(i32x4*)(S + (size_t)(ti * 128 + r2) * NR + tj * 128 + c * 16) = d;
    }
    if (!diag) {
#pragma unroll
      for (int k = 0; k < 4; ++k) {
        int c = half * 4 + k;
        int phys = c ^ (r2 & 7);
        i32x4 d = *(const i32x4*)(mirror + r2 * 128 + phys * 16);
        *(i32x4*)(S + (size_t)(tj * 128 + r2) * NR + ti * 128 + c * 16) = d;
      }
    }
  }
}

// ---------- kernel 3: Yt[n][j] = i8(dinv_j * X[j][n] / sY); dinv from rs ----------
__global__ __launch_bounds__(256) void k_make_yt(const float* __restrict__ X,
                                                 const float* __restrict__ rs_partial,
                                                 i8* __restrict__ Yt) {
  __shared__ float T[64][65];
  int i0 = blockIdx.x * 64, k0 = blockIdx.y * 64;
  int tid = threadIdx.x;
  {
    int iL = tid >> 2, ks = (tid & 3) * 4;
    const float* xr = X + (size_t)(i0 + iL) * DC + k0;
#pragma unroll
    for (int u = 0; u < 4; ++u) {
      float4 f = *(const float4*)(xr + ks + u * 16);
      T[iL][ks + u * 16 + 0] = f.x;
      T[iL][ks + u * 16 + 1] = f.y;
      T[iL][ks + u * 16 + 2] = f.z;
      T[iL][ks + u * 16 + 3] = f.w;
    }
  }
  __syncthreads();
  {
    int kL = tid >> 2, ib = (tid & 3) * 16;
    char pk[16];
#pragma unroll
    for (int u = 0; u < 16; ++u) {
      float dj = rsqrtf(rs_partial[i0 + ib + u] + 1.0f);
      float v = T[ib + u][kL] * dj;
      int q = (int)rintf(v * QY_INV);
      q = q > 127 ? 127 : (q < -127 ? -127 : q);
      pk[u] = (char)q;
    }
    *(i32x4*)(Yt + (size_t)(k0 + kL) * NR + i0 + ib) = *(const i32x4*)pk;
  }
}

// ---------- kernel 4: split-K i8 GEMM partials = S @ Yt^T ----------
// 512 threads, block tile 128x256, BK=128 (16 iters), per-wave 64x64.
__global__ __launch_bounds__(512, 4) void k_outgemm(const i8* __restrict__ S,
                                                    const i8* __restrict__ Yt,
                                                    u16* __restrict__ Pb) {
  __shared__ alignas(16) i8 As[128 * 128];  // 16 KB
  __shared__ alignas(16) i8 Bs[256 * 128];  // 32 KB
  int tid = threadIdx.x, lane = tid & 63, wave = tid >> 6;
  int tn = blockIdx.x, ti = blockIdx.y, kz = blockIdx.z;
  int wm = wave & 1, wn = wave >> 1;  // 2 x 4 wave grid
  int quad = lane >> 4, col = lane & 15;
  i32x4 zero = {0, 0, 0, 0};
  i32x4 acc[4][4];
#pragma unroll
  for (int a = 0; a < 4; ++a)
#pragma unroll
    for (int c = 0; c < 4; ++c) acc[a][c] = zero;

  const int KCH = NR / KZN;
  int k_lo = kz * KCH, k_hi = k_lo + KCH;
  for (int kt = k_lo; kt < k_hi; kt += 128) {
    __syncthreads();
    stage_i8_k128<128, 512>(S, NR, ti * 128, kt, As, tid);
    stage_i8_k128<256, 512>(Yt, NR, tn * 256, kt, Bs, tid);
    __syncthreads();
#pragma unroll
    for (int kc = 0; kc < 2; ++kc) {
      i32x4 af[4], bfr[4];
#pragma unroll
      for (int mi = 0; mi < 4; ++mi)
        af[mi] = frag_i8_k128(As, wm * 64 + mi * 16 + col, kc * 4 + quad);
#pragma unroll
      for (int ni = 0; ni < 4; ++ni)
        bfr[ni] = frag_i8_k128(Bs, wn * 64 + ni * 16 + col, kc * 4 + quad);
#pragma unroll
      for (int mi = 0; mi < 4; ++mi)
#pragma unroll
        for (int ni = 0; ni < 4; ++ni)
          acc[mi][ni] = __builtin_amdgcn_mfma_i32_16x16x64_i8(af[mi], bfr[ni], acc[mi][ni], 0, 0, 0);
    }
  }
#pragma unroll
  for (int mi = 0; mi < 4; ++mi) {
#pragma unroll
    for (int r = 0; r < 4; ++r) {
      int gi = ti * 128 + wm * 64 + mi * 16 + quad * 4 + r;
#pragma unroll
      for (int ni = 0; ni < 4; ++ni) {
        int gj = tn * 256 + wn * 64 + ni * 16 + col;
        Pb[((size_t)kz * NR + gi) * DC + gj] = f2bf((float)acc[mi][ni][r] * DEQ);
      }
    }
  }
}

// ---------- kernel 5: reduce partials + xs*X -> out ----------
__global__ __launch_bounds__(256) void k_reduce(const u16* __restrict__ Pb,
                                               const float* __restrict__ X,
                                               const float* __restrict__ rs_partial,
                                               float* __restrict__ out) {
  const float c1 = (float)(2.0 / 3.0);
  const float c0 = 1.0f - c1;
  size_t idx = ((size_t)blockIdx.x * 256 + threadIdx.x) * 4;
  int i = (int)(idx >> 9);  // row = idx / DC
  float4 s = {0.f, 0.f, 0.f, 0.f};
#pragma unroll
  for (int kz = 0; kz < KZN; ++kz) {
    u16x4 p = *(const u16x4*)(Pb + (size_t)kz * NR * DC + idx);
    s.x += bf2f(p[0]); s.y += bf2f(p[1]); s.z += bf2f(p[2]); s.w += bf2f(p[3]);
  }
  float4 x = *(const float4*)(X + idx);
  float rs = rs_partial[i] + 1.0f;
  float sc = c1 * rsqrtf(rs);
  float xs = c0 + c1 / rs;
  float4 o = {xs * x.x + sc * s.x, xs * x.y + sc * s.y,
              xs * x.z + sc * s.z, xs * x.w + sc * s.w};
  *(float4*)(out + idx) = o;
}

extern "C" void kernel_launch(void* const* d_in, const int* in_sizes, int n_in,
                              void* d_out, int out_size, void* d_ws, size_t ws_size,
                              hipStream_t stream) {
  const float* X = (const float*)d_in[0];
  float* out = (float*)d_out;
  char* ws = (char*)d_ws;
  // ws layout (~109 MB total; >=218 MB confirmed available in R3)
  i8*  S  = (i8*)(ws);                         // 67108864
  i8*  F  = (i8*)(ws + 67108864);              //  4194304
  i8*  Yt = (i8*)(ws + 71303168);              //  4194304
  float* rs_partial = (float*)(ws + 75497472); //    32768
  u16* Pb = (u16*)(ws + 75530240);             // KZN*8192*512*2 = 33554432

  k_normalize<<<dim3(NR), dim3(256), 0, stream>>>(X, F, rs_partial);
  k_simgemm<<<dim3(64 * 65 / 2), dim3(256), 0, stream>>>(F, S, rs_partial);
  k_make_yt<<<dim3(128, 8), dim3(256), 0, stream>>>(X, rs_partial, Yt);
  k_outgemm<<<dim3(2, 64, KZN), dim3(512), 0, stream>>>(S, Yt, Pb);
  k_reduce<<<dim3(NR * DC / 1024), dim3(256), 0, stream>>>(Pb, X, rs_partial, out);
}

// Round 11
// 190.608 us; speedup vs baseline: 1.3869x; 1.3869x over previous
//
#include <hip/hip_runtime.h>

// GraphFilter on MI355X: out = (1/3 + (2/3)/rs_i) X + (2/3) dinv_i * (A @ (dinv .* X))
// A = thr(F F^T, 1e-10), diag 0; rs = rowsum(A)+1; dinv = rs^-1/2.
// R11: base = R7 (staged global_load_lds K-loops, BK=128, i8 everywhere).
// Single change: simgemm's rs atomics (665K device-scope RMWs on 8192 addrs)
// replaced by collision-free plain stores into rs_parts[128][8192]
// (slot 2*ti+wm for col-sums, 2*tj+wn for row-sums; diag writes col-sums
// only -> every slot written exactly once, no init, no atomics), summed by
// a tiny k_dinv kernel. Direct-load K-loops abandoned: fragment BW demand
// (~100 B/cyc/wave) exceeds L1/L2 supply; LDS multicast is structural.

#define NR 8192
#define DC 512
#define KZN 4

typedef unsigned short u16;
typedef signed char i8;
typedef float f32x4 __attribute__((ext_vector_type(4)));
typedef int i32x4 __attribute__((ext_vector_type(4)));
typedef u16 u16x4 __attribute__((ext_vector_type(4)));

// quant scales
#define QF_INV 453.5714285f      // 127/0.28  (|F| <= ~0.25)
#define DEQA   4.8608093e-6f     // (0.28/127)^2
#define QS_INV 254.0f            // 127/0.5   (S in [0,0.5))
#define QY_INV 211.6666666f      // 127/0.6   (|Yt| <= ~0.53)
#define DEQ    1.8600229e-5f     // (0.5/127)*(0.6/127)

__device__ __forceinline__ float bf2f(u16 u) {
  union { unsigned u; float f; } v; v.u = ((unsigned)u) << 16; return v.f;
}
__device__ __forceinline__ u16 f2bf(float f) {
  union { float f; unsigned u; } v; v.f = f;
  unsigned r = v.u + 0x7fffu + ((v.u >> 16) & 1u);
  return (u16)(r >> 16);
}

// async 16B global->LDS (wave-uniform LDS base + lane*16 semantics)
__device__ __forceinline__ void async16(const void* ga, void* la) {
  __builtin_amdgcn_global_load_lds(
      (const __attribute__((address_space(1))) unsigned int*)ga,
      (__attribute__((address_space(3))) unsigned int*)la, 16, 0, 0);
}

// ---- i8 staging, 128-byte rows (BK=128): ROWSx128 i8 tile, NT threads ----
// Phys 16B slot s (row r = s>>3, phys chunk c = s&7) holds global chunk
// kq = c ^ (r&7): XOR spreads fragment ds_read_b128s across bank groups.
template <int ROWS, int NT>
__device__ __forceinline__ void stage_i8_k128(const i8* __restrict__ g, int ld,
                                              int row0, int k0, i8* lds, int tid) {
  constexpr int PER = (ROWS * 8) / NT;
#pragma unroll
  for (int q = 0; q < PER; ++q) {
    int s = q * NT + tid;
    int r = s >> 3;
    int kq = (s & 7) ^ (r & 7);
    async16(g + (size_t)(row0 + r) * ld + (k0 + kq * 16), lds + s * 16);
  }
}
// fragment: row m, chunk c = kc*4 + quad (c in 0..7)
__device__ __forceinline__ i32x4 frag_i8_k128(const i8* lds, int m, int c) {
  int phys = c ^ (m & 7);
  return *(const i32x4*)(lds + m * 128 + phys * 16);
}

// ---------- kernel 1: row L2-normalize X -> F (i8) ----------
__global__ __launch_bounds__(256) void k_normalize(const float* __restrict__ X,
                                                   i8* __restrict__ F) {
  int row = blockIdx.x;
  int tid = threadIdx.x;
  const float* xr = X + (size_t)row * DC;
  float2 v = *(const float2*)(xr + 2 * tid);
  float s = v.x * v.x + v.y * v.y;
#pragma unroll
  for (int off = 32; off; off >>= 1) s += __shfl_down(s, off);
  __shared__ float wsum[4];
  if ((tid & 63) == 0) wsum[tid >> 6] = s;
  __syncthreads();
  float tot = wsum[0] + wsum[1] + wsum[2] + wsum[3];
  float scale = QF_INV / fmaxf(sqrtf(tot), 1e-12f);
  int q0 = (int)rintf(v.x * scale);
  int q1 = (int)rintf(v.y * scale);
  q0 = q0 > 127 ? 127 : (q0 < -127 ? -127 : q0);
  q1 = q1 > 127 ? 127 : (q1 < -127 ? -127 : q1);
  u16 pk = (u16)((q0 & 255) | ((q1 & 255) << 8));
  ((u16*)(F + (size_t)row * DC))[tid] = pk;
}

// ---------- kernel 2: symmetric S = thr(F F^T), diag 0, i8 in / i8 out ----------
// ti<=tj tiles only; BK=128 -> 4 barrier pairs; mirror via 32 KB LDS transpose.
// Row/col sums written as collision-free plain stores into rs_parts.
__global__ __launch_bounds__(256, 4) void k_simgemm(const i8* __restrict__ F,
                                                    i8* __restrict__ S,
                                                    float* __restrict__ rs_parts) {
  __shared__ alignas(16) char smem[32768];
  i8* As = (i8*)smem;            // 128x128 i8 = 16 KB
  i8* Bs = (i8*)(smem + 16384);  // 128x128 i8 = 16 KB
  int tid = threadIdx.x, lane = tid & 63, wave = tid >> 6;
  // triangle decode: block -> (ti <= tj)
  int b = blockIdx.x;
  int tj = (int)((sqrtf(8.f * b + 1.f) - 1.f) * 0.5f);
  while ((tj + 1) * (tj + 2) / 2 <= b) ++tj;
  while (tj * (tj + 1) / 2 > b) --tj;
  int ti = b - tj * (tj + 1) / 2;
  bool diag = (ti == tj);

  int wm = wave >> 1, wn = wave & 1;
  int quad = lane >> 4, col = lane & 15;
  i32x4 zero = {0, 0, 0, 0};
  i32x4 acc[4][4];
#pragma unroll
  for (int a = 0; a < 4; ++a)
#pragma unroll
    for (int c = 0; c < 4; ++c) acc[a][c] = zero;

  const i8* Bsrc = diag ? As : Bs;
  for (int kt = 0; kt < DC; kt += 128) {  // 4 iterations
    __syncthreads();
    stage_i8_k128<128, 256>(F, DC, ti * 128, kt, As, tid);
    if (!diag) stage_i8_k128<128, 256>(F, DC, tj * 128, kt, Bs, tid);
    __syncthreads();
#pragma unroll
    for (int kc = 0; kc < 2; ++kc) {
      i32x4 af[4], bfr[4];
#pragma unroll
      for (int mi = 0; mi < 4; ++mi)
        af[mi] = frag_i8_k128(As, wm * 64 + mi * 16 + col, kc * 4 + quad);
#pragma unroll
      for (int ni = 0; ni < 4; ++ni)
        bfr[ni] = frag_i8_k128(Bsrc, wn * 64 + ni * 16 + col, kc * 4 + quad);
#pragma unroll
      for (int mi = 0; mi < 4; ++mi)
#pragma unroll
        for (int ni = 0; ni < 4; ++ni)
          acc[mi][ni] = __builtin_amdgcn_mfma_i32_16x16x64_i8(af[mi], bfr[ni], acc[mi][ni], 0, 0, 0);
    }
  }

  // dequant + threshold + diag-zero; fused exact column sums and row sums
  float av[4][4][4];
  float cs[4] = {0.f, 0.f, 0.f, 0.f};
  float rv[16];
#pragma unroll
  for (int u = 0; u < 16; ++u) rv[u] = 0.f;
#pragma unroll
  for (int mi = 0; mi < 4; ++mi) {
#pragma unroll
    for (int r = 0; r < 4; ++r) {
      int gi = ti * 128 + wm * 64 + mi * 16 + quad * 4 + r;
#pragma unroll
      for (int ni = 0; ni < 4; ++ni) {
        int gj = tj * 128 + wn * 64 + ni * 16 + col;
        float v = (float)acc[mi][ni][r] * DEQA;
        if (v < 1e-10f || gi == gj) v = 0.f;
        av[mi][ni][r] = v;
        cs[ni] += v;
        rv[mi * 4 + r] += v;
      }
    }
  }
  // col-sums (over this wave's 64 rows): slot 2*ti+wm, plain stores
#pragma unroll
  for (int ni = 0; ni < 4; ++ni) {
    float c = cs[ni];
    c += __shfl_xor(c, 16);
    c += __shfl_xor(c, 32);
    if (quad == 0) {
      int gj = tj * 128 + wn * 64 + ni * 16 + col;
      rs_parts[(size_t)(2 * ti + wm) * NR + gj] = c;
    }
  }
  // row-sums (over this wave's 64 cols): slot 2*tj+wn (off-diag only;
  // diag covered by col-sums). float4-packed per quad.
  if (!diag) {
#pragma unroll
    for (int u = 0; u < 16; ++u) {
      rv[u] += __shfl_xor(rv[u], 1);
      rv[u] += __shfl_xor(rv[u], 2);
      rv[u] += __shfl_xor(rv[u], 4);
      rv[u] += __shfl_xor(rv[u], 8);
    }
    if (col == 0) {
#pragma unroll
      for (int mi = 0; mi < 4; ++mi) {
        int gi = ti * 128 + wm * 64 + mi * 16 + quad * 4;
        float4 pk = {rv[mi * 4 + 0], rv[mi * 4 + 1], rv[mi * 4 + 2], rv[mi * 4 + 3]};
        *(float4*)(rs_parts + (size_t)(2 * tj + wn) * NR + gi) = pk;
      }
    }
  }

  // quantize + single-pass LDS transpose; 16B-chunk XOR swizzle per row
  char* direct = smem;           // 128x128 i8 = 16 KB
  char* mirror = smem + 16384;   // 128x128 i8 = 16 KB
  __syncthreads();
#pragma unroll
  for (int mi = 0; mi < 4; ++mi) {
#pragma unroll
    for (int ni = 0; ni < 4; ++ni) {
      int cg = wn * 64 + ni * 16 + col;
      int q[4];
#pragma unroll
      for (int r = 0; r < 4; ++r) {
        int qq = (int)rintf(av[mi][ni][r] * QS_INV);
        q[r] = qq > 127 ? 127 : qq;
      }
#pragma unroll
      for (int r = 0; r < 4; ++r) {
        int row = wm * 64 + mi * 16 + quad * 4 + r;
        int chunk = (cg >> 4) ^ (row & 7);
        direct[row * 128 + chunk * 16 + (cg & 15)] = (char)q[r];
      }
      if (!diag) {
        int mcb = wm * 64 + mi * 16 + quad * 4;
        int chunk = (mcb >> 4) ^ (cg & 7);
        unsigned pk = (unsigned)(q[0] & 255) | ((unsigned)(q[1] & 255) << 8) |
                      ((unsigned)(q[2] & 255) << 16) | ((unsigned)(q[3] & 255) << 24);
        *(unsigned*)(mirror + cg * 128 + chunk * 16 + (mcb & 15)) = pk;
      }
    }
  }
  __syncthreads();
  // coalesced 16B global stores
  {
    int r2 = tid >> 1, half = tid & 1;
#pragma unroll
    for (int k = 0; k < 4; ++k) {
      int c = half * 4 + k;
      int phys = c ^ (r2 & 7);
      i32x4 d = *(const i32x4*)(direct + r2 * 128 + phys * 16);
      *(i32x4*)(S + (size_t)(ti * 128 + r2) * NR + tj * 128 + c * 16) = d;
    }
    if (!diag) {
#pragma unroll
      for (int k = 0; k < 4; ++k) {
        int c = half * 4 + k;
        int phys = c ^ (r2 & 7);
        i32x4 d = *(const i32x4*)(mirror + r2 * 128 + phys * 16);
        *(i32x4*)(S + (size_t)(tj * 128 + r2) * NR + ti * 128 + c * 16) = d;
      }
    }
  }
}

// ---------- kernel 3: rs_partial[i] = sum over 128 slots of rs_parts ----------
__global__ __launch_bounds__(256) void k_dinv(const float* __restrict__ rs_parts,
                                              float* __restrict__ rs_partial) {
  int i = blockIdx.x * 256 + threadIdx.x;
  float s = 0.f;
#pragma unroll 8
  for (int p = 0; p < 128; ++p) s += rs_parts[(size_t)p * NR + i];
  rs_partial[i] = s;
}

// ---------- kernel 4: Yt[n][j] = i8(dinv_j * X[j][n] / sY); dinv from rs ----------
__global__ __launch_bounds__(256) void k_make_yt(const float* __restrict__ X,
                                                 const float* __restrict__ rs_partial,
                                                 i8* __restrict__ Yt) {
  __shared__ float T[64][65];
  int i0 = blockIdx.x * 64, k0 = blockIdx.y * 64;
  int tid = threadIdx.x;
  {
    int iL = tid >> 2, ks = (tid & 3) * 4;
    const float* xr = X + (size_t)(i0 + iL) * DC + k0;
#pragma unroll
    for (int u = 0; u < 4; ++u) {
      float4 f = *(const float4*)(xr + ks + u * 16);
      T[iL][ks + u * 16 + 0] = f.x;
      T[iL][ks + u * 16 + 1] = f.y;
      T[iL][ks + u * 16 + 2] = f.z;
      T[iL][ks + u * 16 + 3] = f.w;
    }
  }
  __syncthreads();
  {
    int kL = tid >> 2, ib = (tid & 3) * 16;
    char pk[16];
#pragma unroll
    for (int u = 0; u < 16; ++u) {
      float dj = rsqrtf(rs_partial[i0 + ib + u] + 1.0f);
      float v = T[ib + u][kL] * dj;
      int q = (int)rintf(v * QY_INV);
      q = q > 127 ? 127 : (q < -127 ? -127 : q);
      pk[u] = (char)q;
    }
    *(i32x4*)(Yt + (size_t)(k0 + kL) * NR + i0 + ib) = *(const i32x4*)pk;
  }
}

// ---------- kernel 5: split-K i8 GEMM partials = S @ Yt^T ----------
// 512 threads, block tile 128x256, BK=128 (16 iters), per-wave 64x64.
__global__ __launch_bounds__(512, 4) void k_outgemm(const i8* __restrict__ S,
                                                    const i8* __restrict__ Yt,
                                                    u16* __restrict__ Pb) {
  __shared__ alignas(16) i8 As[128 * 128];  // 16 KB
  __shared__ alignas(16) i8 Bs[256 * 128];  // 32 KB
  int tid = threadIdx.x, lane = tid & 63, wave = tid >> 6;
  int tn = blockIdx.x, ti = blockIdx.y, kz = blockIdx.z;
  int wm = wave & 1, wn = wave >> 1;  // 2 x 4 wave grid
  int quad = lane >> 4, col = lane & 15;
  i32x4 zero = {0, 0, 0, 0};
  i32x4 acc[4][4];
#pragma unroll
  for (int a = 0; a < 4; ++a)
#pragma unroll
    for (int c = 0; c < 4; ++c) acc[a][c] = zero;

  const int KCH = NR / KZN;
  int k_lo = kz * KCH, k_hi = k_lo + KCH;
  for (int kt = k_lo; kt < k_hi; kt += 128) {
    __syncthreads();
    stage_i8_k128<128, 512>(S, NR, ti * 128, kt, As, tid);
    stage_i8_k128<256, 512>(Yt, NR, tn * 256, kt, Bs, tid);
    __syncthreads();
#pragma unroll
    for (int kc = 0; kc < 2; ++kc) {
      i32x4 af[4], bfr[4];
#pragma unroll
      for (int mi = 0; mi < 4; ++mi)
        af[mi] = frag_i8_k128(As, wm * 64 + mi * 16 + col, kc * 4 + quad);
#pragma unroll
      for (int ni = 0; ni < 4; ++ni)
        bfr[ni] = frag_i8_k128(Bs, wn * 64 + ni * 16 + col, kc * 4 + quad);
#pragma unroll
      for (int mi = 0; mi < 4; ++mi)
#pragma unroll
        for (int ni = 0; ni < 4; ++ni)
          acc[mi][ni] = __builtin_amdgcn_mfma_i32_16x16x64_i8(af[mi], bfr[ni], acc[mi][ni], 0, 0, 0);
    }
  }
#pragma unroll
  for (int mi = 0; mi < 4; ++mi) {
#pragma unroll
    for (int r = 0; r < 4; ++r) {
      int gi = ti * 128 + wm * 64 + mi * 16 + quad * 4 + r;
#pragma unroll
      for (int ni = 0; ni < 4; ++ni) {
        int gj = tn * 256 + wn * 64 + ni * 16 + col;
        Pb[((size_t)kz * NR + gi) * DC + gj] = f2bf((float)acc[mi][ni][r] * DEQ);
      }
    }
  }
}

// ---------- kernel 6: reduce partials + xs*X -> out ----------
__global__ __launch_bounds__(256) void k_reduce(const u16* __restrict__ Pb,
                                               const float* __restrict__ X,
                                               const float* __restrict__ rs_partial,
                                               float* __restrict__ out) {
  const float c1 = (float)(2.0 / 3.0);
  const float c0 = 1.0f - c1;
  size_t idx = ((size_t)blockIdx.x * 256 + threadIdx.x) * 4;
  int i = (int)(idx >> 9);  // row = idx / DC
  float4 s = {0.f, 0.f, 0.f, 0.f};
#pragma unroll
  for (int kz = 0; kz < KZN; ++kz) {
    u16x4 p = *(const u16x4*)(Pb + (size_t)kz * NR * DC + idx);
    s.x += bf2f(p[0]); s.y += bf2f(p[1]); s.z += bf2f(p[2]); s.w += bf2f(p[3]);
  }
  float4 x = *(const float4*)(X + idx);
  float rs = rs_partial[i] + 1.0f;
  float sc = c1 * rsqrtf(rs);
  float xs = c0 + c1 / rs;
  float4 o = {xs * x.x + sc * s.x, xs * x.y + sc * s.y,
              xs * x.z + sc * s.z, xs * x.w + sc * s.w};
  *(float4*)(out + idx) = o;
}

extern "C" void kernel_launch(void* const* d_in, const int* in_sizes, int n_in,
                              void* d_out, int out_size, void* d_ws, size_t ws_size,
                              hipStream_t stream) {
  const float* X = (const float*)d_in[0];
  float* out = (float*)d_out;
  char* ws = (char*)d_ws;
  // ws layout (~113 MB total; >=218 MB confirmed available in R3)
  i8*  S  = (i8*)(ws);                         // 67108864
  i8*  F  = (i8*)(ws + 67108864);              //  4194304
  i8*  Yt = (i8*)(ws + 71303168);              //  4194304
  float* rs_partial = (float*)(ws + 75497472); //    32768
  float* rs_parts   = (float*)(ws + 75530240); // 128*8192*4 = 4194304
  u16* Pb = (u16*)(ws + 79724544);             // KZN*8192*512*2 = 33554432

  k_normalize<<<dim3(NR), dim3(256), 0, stream>>>(X, F);
  k_simgemm<<<dim3(64 * 65 / 2), dim3(256), 0, stream>>>(F, S, rs_parts);
  k_dinv<<<dim3(NR / 256), dim3(256), 0, stream>>>(rs_parts, rs_partial);
  k_make_yt<<<dim3(128, 8), dim3(256), 0, stream>>>(X, rs_partial, Yt);
  k_outgemm<<<dim3(2, 64, KZN), dim3(512), 0, stream>>>(S, Yt, Pb);
  k_reduce<<<dim3(NR * DC / 1024), dim3(256), 0, stream>>>(Pb, X, rs_partial, out);
}